// Round 8
// baseline (1178.877 us; speedup 1.0000x reference)
//
#include <hip/hip_runtime.h>
#include <stdint.h>
#include <math.h>

#define NN 12288
#define DD 128
#define KTOP 31
#define TCAND 64         // candidate set >= top-64 by bf16 key (verified margin)
#define CCAP 128         // compaction capacity
#define RPB 16           // rows per block; grid = 768
#define WPB 8            // waves per block (512 threads)
#define LDEP 14          // ladder depth; 32 streams x 14 = 448 keys/row (R6/R7-verified)
#define NSTREAM 32
#define KPR (NSTREAM * LDEP)   // 448 keys per row
#define KPL (KPR / 64)         // 7 keys per lane
#define SC 128           // columns staged per stage (32 KB)
#define NST (NN / SC)    // 96 stages

typedef __attribute__((ext_vector_type(8))) short bf16x8;
typedef __attribute__((ext_vector_type(4))) float f32x4;

__device__ __forceinline__ unsigned short f2bf(float x) {  // RNE, no NaN in our data
  unsigned int u = __float_as_uint(x);
  u += 0x7fffu + ((u >> 16) & 1u);
  return (unsigned short)(u >> 16);
}

// med3(p, L[i], L[i+1]) == sorted-ladder insert step
__device__ __forceinline__ unsigned umed3(unsigned a, unsigned b, unsigned c) {
  unsigned d;
  asm("v_med3_u32 %0, %1, %2, %3" : "=v"(d) : "v"(a), "v"(b), "v"(c));
  return d;
}

#define PINS(P) { \
  const unsigned p_ = (P); \
  _Pragma("unroll") \
  for (int i_ = 0; i_ < LDEP - 1; ++i_) \
    L[i_] = umed3(p_, L[i_], L[i_ + 1]); \
  L[LDEP - 1] = L[LDEP - 1] > p_ ? L[LDEP - 1] : p_; }

// ---------------- Kernel 0: transpose W1,W2 so mlp reads are coalesced ----------------
__global__ __launch_bounds__(128)
void wtrans_kernel(const float* __restrict__ W1, const float* __restrict__ W2,
                   float* __restrict__ W1T, float* __restrict__ W2T) {
  const int r = blockIdx.x, c = threadIdx.x;
  W1T[(size_t)c * DD + r] = W1[(size_t)r * DD + c];
  W2T[(size_t)c * DD + r] = W2[(size_t)r * DD + c];
}

// ---------------- Kernel 1: MLP + L2 normalize (256 thr / 16 rows per block) ----------------
__global__ __launch_bounds__(256)
void mlp_norm_kernel(const float* __restrict__ feat,
                     const float* __restrict__ W1T, const float* __restrict__ b1,
                     const float* __restrict__ W2T, const float* __restrict__ b2,
                     double* __restrict__ hn64, unsigned short* __restrict__ hnb) {
  __shared__ double bufA[16][DD];
  __shared__ double bufB[16][DD];
  __shared__ double mnorm[16];
  const int t = threadIdx.x;
  const int c = t & 127;         // column
  const int g = t >> 7;          // row-group (0/1): rows g*8 .. g*8+7
  const int row0 = blockIdx.x * 16 + g * 8;

  #pragma unroll
  for (int rr = 0; rr < 8; ++rr)
    bufA[g * 8 + rr][c] = (double)feat[(size_t)(row0 + rr) * DD + c];
  __syncthreads();

  {
    double acc[8] = {0,0,0,0,0,0,0,0};
    for (int k = 0; k < DD; k += 2) {
      double w0 = (double)W1T[(size_t)k * DD + c];
      double w1 = (double)W1T[(size_t)(k + 1) * DD + c];
      #pragma unroll
      for (int rr = 0; rr < 8; ++rr) {
        double2 a2 = *(const double2*)(&bufA[g * 8 + rr][k]);
        acc[rr] = fma(w0, a2.x, acc[rr]);
        acc[rr] = fma(w1, a2.y, acc[rr]);
      }
    }
    double bb = (double)b1[c];
    #pragma unroll
    for (int rr = 0; rr < 8; ++rr)
      bufB[g * 8 + rr][c] = fmax(acc[rr] + bb, 0.0);
  }
  __syncthreads();
  {
    double acc[8] = {0,0,0,0,0,0,0,0};
    for (int k = 0; k < DD; k += 2) {
      double w0 = (double)W2T[(size_t)k * DD + c];
      double w1 = (double)W2T[(size_t)(k + 1) * DD + c];
      #pragma unroll
      for (int rr = 0; rr < 8; ++rr) {
        double2 a2 = *(const double2*)(&bufB[g * 8 + rr][k]);
        acc[rr] = fma(w0, a2.x, acc[rr]);
        acc[rr] = fma(w1, a2.y, acc[rr]);
      }
    }
    double bb = (double)b2[c];
    #pragma unroll
    for (int rr = 0; rr < 8; ++rr)
      bufA[g * 8 + rr][c] = acc[rr] + bb;
  }
  __syncthreads();

  const int lane = t & 63;
  const int w = t >> 6;
  #pragma unroll
  for (int r2 = 0; r2 < 4; ++r2) {
    int rr = w * 4 + r2;
    double x0 = bufA[rr][lane];
    double x1 = bufA[rr][lane + 64];
    double s = x0 * x0 + x1 * x1;
    #pragma unroll
    for (int d = 1; d < 64; d <<= 1)
      s += __shfl_xor(s, d);
    if (lane == 0) mnorm[rr] = fmax(sqrt(s), 1e-12);
  }
  __syncthreads();
  #pragma unroll
  for (int rr = 0; rr < 8; ++rr) {
    double v = bufA[g * 8 + rr][c] / mnorm[g * 8 + rr];
    hn64[(size_t)(row0 + rr) * DD + c] = v;
    hnb[(size_t)(row0 + rr) * DD + c] = f2bf((float)v);
  }
}

// ---------------- Kernel 2: sim + top-select + fp64 rescore, LDS-staged loop ----------------
// R8: canonical async staging. Per stage: issue next stage's 32 KB via
// global_load_lds (pre-swizzled source), compute current stage from LDS
// (swizzled ds_read_b128 -> bit-identical b-fragments), 4 MFMAs + 4 ladder
// inserts per wave, one __syncthreads per stage (drains prefetch under
// compute). Swizzle: chunk' = chunk ^ (col&7) on BOTH writer-source and
// reader (rule #21) -> ~2-way banks (free). Tail verbatim from R7.
__global__ __launch_bounds__(512, 2)
void simsel_kernel(const unsigned short* __restrict__ hnb,
                   const double* __restrict__ hn64,
                   float* __restrict__ resval, int* __restrict__ rescol) {
  __shared__ __attribute__((aligned(16))) unsigned short stage[2][SC * DD]; // 2 x 32 KB
  __shared__ unsigned keybuf[RPB][KPR + 1];   // 28.7 KB
  __shared__ unsigned scand[WPB][CCAP];       // 4 KB
  __shared__ double cres[WPB][CCAP];          // 8 KB
  const int t = threadIdx.x, lane = t & 63, wv = t >> 6;
  const int m = lane & 15, quad = lane >> 4;
  const int row0 = blockIdx.x * RPB;

  // afrag: MFMA B-operand (rows row0+m), from global (verified mapping)
  bf16x8 afrag[4];
  #pragma unroll
  for (int kc = 0; kc < 4; ++kc)
    afrag[kc] = *(const bf16x8*)(hnb + (size_t)(row0 + m) * DD + kc * 32 + quad * 8);

  // staging: thread t, issue i covers LDS chunk u = i*512+t (16 B chunks,
  // col = u>>4, slot-chunk cL = u&15). Slot (col,cL) holds GLOBAL chunk
  // cL ^ (col&7) of column col -> pre-swizzled source address.
  const unsigned short* gsrc[4];
  unsigned ldsb[4];
  #pragma unroll
  for (int i = 0; i < 4; ++i) {
    int u = i * 512 + t;
    int col = u >> 4;
    int ch = (u & 15) ^ (col & 7);
    gsrc[i] = hnb + (size_t)col * DD + ch * 8;
    ldsb[i] = (unsigned)(i * 8192 + wv * 1024);   // wave-uniform byte base
  }

  // reader offsets (bytes, per-lane constants): col_local = wv*16+m,
  // global chunk (kc*4+quad) lives at slot (kc*4+quad)^(m&7)
  unsigned roff[4];
  #pragma unroll
  for (int kc = 0; kc < 4; ++kc)
    roff[kc] = (unsigned)((wv * 16 + m) * 256 + (((kc * 4 + quad) ^ (m & 7)) * 16));

  unsigned L[LDEP];
  #pragma unroll
  for (int i = 0; i < LDEP; ++i) L[i] = 0;

  // prologue: stage 0
  {
    char* dst = (char*)stage[0];
    #pragma unroll
    for (int i = 0; i < 4; ++i)
      __builtin_amdgcn_global_load_lds((const void*)gsrc[i], (void*)(dst + ldsb[i]), 16, 0, 0);
  }
  __syncthreads();   // drains vmcnt -> stage 0 resident

  for (int s = 0; s < NST; ++s) {
    // issue next stage into the other buffer (overlaps with compute below)
    if (s + 1 < NST) {
      char* dst = (char*)stage[(s + 1) & 1];
      const size_t gadd = (size_t)(s + 1) * (SC * DD);
      #pragma unroll
      for (int i = 0; i < 4; ++i)
        __builtin_amdgcn_global_load_lds((const void*)(gsrc[i] + gadd),
                                         (void*)(dst + ldsb[i]), 16, 0, 0);
    }
    // compute stage s from LDS
    const char* buf = (const char*)stage[s & 1];
    f32x4 acc = {0.0f, 0.0f, 0.0f, 0.0f};
    #pragma unroll
    for (int kc = 0; kc < 4; ++kc) {
      bf16x8 b = *(const bf16x8*)(buf + roff[kc]);
      acc = __builtin_amdgcn_mfma_f32_16x16x32_bf16(b, afrag[kc], acc, 0, 0, 0);
    }
    const int cbw = s * SC + wv * 16;    // this wave's 16-col tile base
    #pragma unroll
    for (int r = 0; r < 4; ++r) {
      unsigned bf = f2bf(acc[r]);
      unsigned sc = (bf & 0x8000u) ? 0u : bf;   // clamp negatives to rank 0
      unsigned p = (sc << 16) | (unsigned)(cbw + quad * 4 + r);
      PINS(p)
    }
    __syncthreads();   // all reads of buf[s&1] done; next stage's loads drained
  }

  // dump ladders: row m, stream id wv*4+quad
  #pragma unroll
  for (int d = 0; d < LDEP; ++d)
    keybuf[m][(wv * 4 + quad) * LDEP + d] = L[d];
  __syncthreads();

  // per-row (2 rows per wave): threshold select + coalesced fp64 rescore + top-31
  for (int ii = 0; ii < 2; ++ii) {
    const int lr = wv * 2 + ii;
    const int grow = row0 + lr;
    unsigned k7[KPL];
    #pragma unroll
    for (int i = 0; i < KPL; ++i)
      k7[i] = keybuf[lr][lane * KPL + i];

    unsigned lo = 0, hi = 0xFFFFu;
    while (lo < hi) {
      unsigned mid = (lo + hi + 1) >> 1;
      int c = 0;
      #pragma unroll
      for (int i = 0; i < KPL; ++i) c += (int)((k7[i] >> 16) >= mid);
      #pragma unroll
      for (int d = 1; d < 64; d <<= 1) c += __shfl_xor(c, d);
      if (c >= TCAND) lo = mid; else hi = mid - 1;
    }
    const unsigned thr = lo;

    int cl = 0;
    #pragma unroll
    for (int i = 0; i < KPL; ++i) cl += (int)((k7[i] >> 16) >= thr);
    int pre = cl;
    #pragma unroll
    for (int d = 1; d < 64; d <<= 1) {
      int y = __shfl_up(pre, d);
      if (lane >= d) pre += y;
    }
    const int total = __shfl(pre, 63);
    const int nc = total < CCAP ? total : CCAP;
    int slot = pre - cl;
    #pragma unroll
    for (int i = 0; i < KPL; ++i) {
      if ((k7[i] >> 16) >= thr) {
        if (slot < CCAP) scand[wv][slot] = k7[i];
        ++slot;
      }
    }
    // same-wave LDS producer->consumer: compiler inserts lgkmcnt

    const double* arow = hn64 + (size_t)grow * DD;
    const int hl = lane >> 5;
    const int kl = (lane & 31) * 4;
    const double a0 = arow[kl], a1 = arow[kl + 1], a2 = arow[kl + 2], a3 = arow[kl + 3];
    const int ng = (nc + 1) >> 1;
    for (int g = 0; g < ng; ++g) {
      const int ci = 2 * g + hl;
      double partial = 0.0;
      if (ci < nc) {
        const int col = (int)(scand[wv][ci] & 0xFFFFu);
        const double* brow = hn64 + (size_t)col * DD + kl;
        double2 b01 = *(const double2*)(brow);
        double2 b23 = *(const double2*)(brow + 2);
        partial = fma(a0, b01.x, fma(a1, b01.y, fma(a2, b23.x, a3 * b23.y)));
      }
      #pragma unroll
      for (int d = 1; d < 32; d <<= 1)
        partial += __shfl_xor(partial, d);
      if ((lane & 31) == 0 && ci < nc) cres[wv][ci] = partial;
    }
    double rv0 = -1.0e300, rv1 = -1.0e300;
    int rc0 = 0x7fffffff, rc1 = 0x7fffffff;
    if (lane < nc)      { rv0 = cres[wv][lane];      rc0 = (int)(scand[wv][lane] & 0xFFFFu); }
    if (lane + 64 < nc) { rv1 = cres[wv][lane + 64]; rc1 = (int)(scand[wv][lane + 64] & 0xFFFFu); }

    for (int itk = 0; itk < KTOP; ++itk) {
      bool f = (rv0 > rv1) || (rv0 == rv1 && rc0 < rc1);
      double bv = f ? rv0 : rv1;
      int bc = f ? rc0 : rc1;
      #pragma unroll
      for (int d = 1; d < 64; d <<= 1) {
        double ov = __shfl_xor(bv, d);
        int    oc = __shfl_xor(bc, d);
        bool tk = (ov > bv) || (ov == bv && oc < bc);
        bv = tk ? ov : bv;
        bc = tk ? oc : bc;
      }
      if (lane == itk) {
        resval[(size_t)grow * KTOP + itk] = (float)fmax(bv, 0.0);
        rescol[(size_t)grow * KTOP + itk] = bc;
      }
      if (rv0 == bv && rc0 == bc) rv0 = -1.0e300;
      else if (rv1 == bv && rc1 == bc) rv1 = -1.0e300;
    }
  }
}

// ---------------- Kernel 3: emit all rows (zeros + 31 scattered values) ----------------
__global__ __launch_bounds__(256)
void emit_kernel(const float* __restrict__ resval, const int* __restrict__ rescol,
                 float* __restrict__ out) {
  const int row = blockIdx.x, t = threadIdx.x;
  float v = 0.0f; int c = 0;
  if (t < KTOP) {
    v = resval[(size_t)row * KTOP + t];
    c = rescol[(size_t)row * KTOP + t];
  }
  f32x4* orow = (f32x4*)(out + (size_t)row * NN);
  const f32x4 z = {0.0f, 0.0f, 0.0f, 0.0f};
  #pragma unroll
  for (int i = 0; i < NN / 4 / 256; ++i)
    __builtin_nontemporal_store(z, &orow[i * 256 + t]);
  __syncthreads();   // zeros drained before scatter overwrites
  if (t < KTOP) out[(size_t)row * NN + c] = v;
}

extern "C" void kernel_launch(void* const* d_in, const int* in_sizes, int n_in,
                              void* d_out, int out_size, void* d_ws, size_t ws_size,
                              hipStream_t stream) {
  const float* feat = (const float*)d_in[0];
  const float* W1 = (const float*)d_in[1];
  const float* b1 = (const float*)d_in[2];
  const float* W2 = (const float*)d_in[3];
  const float* b2 = (const float*)d_in[4];
  float* out = (float*)d_out;

  // ws: hn64 (12.6 MB) | hnb (3.1 MB) | resval (1.5 MB) | rescol (1.5 MB) | W1T,W2T (128 KB)
  double* hn64 = (double*)d_ws;
  unsigned short* hnb = (unsigned short*)(hn64 + (size_t)NN * DD);
  float* resval = (float*)(hnb + (size_t)NN * DD);
  int* rescol = (int*)(resval + (size_t)NN * KTOP);
  float* W1T = (float*)(rescol + (size_t)NN * KTOP);
  float* W2T = W1T + DD * DD;

  wtrans_kernel<<<DD, DD, 0, stream>>>(W1, W2, W1T, W2T);
  mlp_norm_kernel<<<NN / 16, 256, 0, stream>>>(feat, W1T, b1, W2T, b2, hn64, hnb);
  simsel_kernel<<<NN / RPB, 512, 0, stream>>>(hnb, hn64, resval, rescol);
  emit_kernel<<<NN, 256, 0, stream>>>(resval, rescol, out);
}

// Round 9
// 1092.669 us; speedup vs baseline: 1.0789x; 1.0789x over previous
//
#include <hip/hip_runtime.h>
#include <stdint.h>
#include <math.h>

#define NN 12288
#define DD 128
#define KTOP 31
#define TCAND 64         // candidate set >= top-64 by bf16 key (R0-R5-verified margin)
#define CCAP 128         // compaction capacity
#define RPB 16           // rows per block; grid = 768
#define WPB 8            // waves per block (512 threads)
#define LDEP 8           // per-stream ladder depth; 64 streams x 8 = 512 keys/row
#define ITERS 48         // column iterations: 12288 / (WPB*32)

typedef __attribute__((ext_vector_type(8))) short bf16x8;
typedef __attribute__((ext_vector_type(4))) float f32x4;

__device__ __forceinline__ unsigned short f2bf(float x) {  // RNE, no NaN in our data
  unsigned int u = __float_as_uint(x);
  u += 0x7fffu + ((u >> 16) & 1u);
  return (unsigned short)(u >> 16);
}

// med3(p, L[i], L[i+1]) == sorted-ladder insert step
__device__ __forceinline__ unsigned umed3(unsigned a, unsigned b, unsigned c) {
  unsigned d;
  asm("v_med3_u32 %0, %1, %2, %3" : "=v"(d) : "v"(a), "v"(b), "v"(c));
  return d;
}

#define PINS8(Lx, P) { \
  const unsigned p_ = (P); \
  _Pragma("unroll") \
  for (int i_ = 0; i_ < 7; ++i_) \
    Lx[i_] = umed3(p_, Lx[i_], Lx[i_ + 1]); \
  Lx[7] = Lx[7] > p_ ? Lx[7] : p_; }

// ---------------- Kernel 0: transpose W1,W2 so mlp reads are coalesced ----------------
__global__ __launch_bounds__(128)
void wtrans_kernel(const float* __restrict__ W1, const float* __restrict__ W2,
                   float* __restrict__ W1T, float* __restrict__ W2T) {
  const int r = blockIdx.x, c = threadIdx.x;
  W1T[(size_t)c * DD + r] = W1[(size_t)r * DD + c];
  W2T[(size_t)c * DD + r] = W2[(size_t)r * DD + c];
}

// ---------------- Kernel 1: MLP + L2 normalize (256 thr / 16 rows per block) ----------------
__global__ __launch_bounds__(256)
void mlp_norm_kernel(const float* __restrict__ feat,
                     const float* __restrict__ W1T, const float* __restrict__ b1,
                     const float* __restrict__ W2T, const float* __restrict__ b2,
                     double* __restrict__ hn64, unsigned short* __restrict__ hnb) {
  __shared__ double bufA[16][DD];
  __shared__ double bufB[16][DD];
  __shared__ double mnorm[16];
  const int t = threadIdx.x;
  const int c = t & 127;         // column
  const int g = t >> 7;          // row-group (0/1)
  const int row0 = blockIdx.x * 16 + g * 8;

  #pragma unroll
  for (int rr = 0; rr < 8; ++rr)
    bufA[g * 8 + rr][c] = (double)feat[(size_t)(row0 + rr) * DD + c];
  __syncthreads();

  {
    double acc[8] = {0,0,0,0,0,0,0,0};
    for (int k = 0; k < DD; k += 2) {
      double w0 = (double)W1T[(size_t)k * DD + c];
      double w1 = (double)W1T[(size_t)(k + 1) * DD + c];
      #pragma unroll
      for (int rr = 0; rr < 8; ++rr) {
        double2 a2 = *(const double2*)(&bufA[g * 8 + rr][k]);
        acc[rr] = fma(w0, a2.x, acc[rr]);
        acc[rr] = fma(w1, a2.y, acc[rr]);
      }
    }
    double bb = (double)b1[c];
    #pragma unroll
    for (int rr = 0; rr < 8; ++rr)
      bufB[g * 8 + rr][c] = fmax(acc[rr] + bb, 0.0);
  }
  __syncthreads();
  {
    double acc[8] = {0,0,0,0,0,0,0,0};
    for (int k = 0; k < DD; k += 2) {
      double w0 = (double)W2T[(size_t)k * DD + c];
      double w1 = (double)W2T[(size_t)(k + 1) * DD + c];
      #pragma unroll
      for (int rr = 0; rr < 8; ++rr) {
        double2 a2 = *(const double2*)(&bufB[g * 8 + rr][k]);
        acc[rr] = fma(w0, a2.x, acc[rr]);
        acc[rr] = fma(w1, a2.y, acc[rr]);
      }
    }
    double bb = (double)b2[c];
    #pragma unroll
    for (int rr = 0; rr < 8; ++rr)
      bufA[g * 8 + rr][c] = acc[rr] + bb;
  }
  __syncthreads();

  const int lane = t & 63;
  const int w = t >> 6;
  #pragma unroll
  for (int r2 = 0; r2 < 4; ++r2) {
    int rr = w * 4 + r2;
    double x0 = bufA[rr][lane];
    double x1 = bufA[rr][lane + 64];
    double s = x0 * x0 + x1 * x1;
    #pragma unroll
    for (int d = 1; d < 64; d <<= 1)
      s += __shfl_xor(s, d);
    if (lane == 0) mnorm[rr] = fmax(sqrt(s), 1e-12);
  }
  __syncthreads();
  #pragma unroll
  for (int rr = 0; rr < 8; ++rr) {
    double v = bufA[g * 8 + rr][c] / mnorm[g * 8 + rr];
    hn64[(size_t)(row0 + rr) * DD + c] = v;
    hnb[(size_t)(row0 + rr) * DD + c] = f2bf((float)v);
  }
}

// ---------------- Kernel 2a: sim MFMA loop + per-lane dual depth-8 ladders ----------------
// R9 attribution split, part 1. R7's proven flat-load loop (no LDS, no
// barriers). Ladder config: acc0->LA, acc1->LB = 64 streams x depth 8 per
// row (the R0-R5-verified margin config; stream length 192). Ladders dumped
// to kbuf (25 MB, parked in d_out's upper region, consumed before emit).
__global__ __launch_bounds__(512, 6)
void simladder_kernel(const unsigned short* __restrict__ hnb,
                      unsigned* __restrict__ kbuf) {
  const int t = threadIdx.x, lane = t & 63, wv = t >> 6;
  const int m = lane & 15, quad = lane >> 4;
  const int row0 = blockIdx.x * RPB;

  bf16x8 afrag[4];
  #pragma unroll
  for (int kc = 0; kc < 4; ++kc)
    afrag[kc] = *(const bf16x8*)(hnb + (size_t)(row0 + m) * DD + kc * 32 + quad * 8);

  unsigned LA[8] = {0,0,0,0,0,0,0,0};
  unsigned LB[8] = {0,0,0,0,0,0,0,0};

  for (int it = 0; it < ITERS; ++it) {
    const int cb = it * (WPB * 32) + wv * 32;
    f32x4 acc0 = {0.0f, 0.0f, 0.0f, 0.0f};
    f32x4 acc1 = {0.0f, 0.0f, 0.0f, 0.0f};
    #pragma unroll
    for (int kc = 0; kc < 4; ++kc) {
      bf16x8 b0 = *(const bf16x8*)(hnb + (size_t)(cb + m) * DD + kc * 32 + quad * 8);
      bf16x8 b1 = *(const bf16x8*)(hnb + (size_t)(cb + 16 + m) * DD + kc * 32 + quad * 8);
      acc0 = __builtin_amdgcn_mfma_f32_16x16x32_bf16(b0, afrag[kc], acc0, 0, 0, 0);
      acc1 = __builtin_amdgcn_mfma_f32_16x16x32_bf16(b1, afrag[kc], acc1, 0, 0, 0);
    }
    #pragma unroll
    for (int r = 0; r < 4; ++r) {
      {
        unsigned bf = f2bf(acc0[r]);
        unsigned s = (bf & 0x8000u) ? 0u : bf;   // clamp negatives to rank 0
        unsigned p = (s << 16) | (unsigned)(cb + quad * 4 + r);
        PINS8(LA, p)
      }
      {
        unsigned bf = f2bf(acc1[r]);
        unsigned s = (bf & 0x8000u) ? 0u : bf;
        unsigned p = (s << 16) | (unsigned)(cb + 16 + quad * 4 + r);
        PINS8(LB, p)
      }
    }
  }

  // dump: row = row0+m owns 512 contiguous u32; this lane's two streams at
  // (wv*4+quad)*16. 4x uint4 stores, 64 B per lane.
  unsigned* dst = kbuf + (size_t)(row0 + m) * 512 + (wv * 4 + quad) * 16;
  *(uint4*)(dst)      = make_uint4(LA[0], LA[1], LA[2], LA[3]);
  *(uint4*)(dst + 4)  = make_uint4(LA[4], LA[5], LA[6], LA[7]);
  *(uint4*)(dst + 8)  = make_uint4(LB[0], LB[1], LB[2], LB[3]);
  *(uint4*)(dst + 12) = make_uint4(LB[4], LB[5], LB[6], LB[7]);
}

// ---------------- Kernel 2b: threshold select + coalesced fp64 rescore + top-31 ----------------
// R9 attribution split, part 2. One wave per row; lane holds one 8-key
// stream (two coalesced uint4 loads). Tail logic verbatim from R2-R8.
__global__ __launch_bounds__(256)
void select_kernel(const unsigned* __restrict__ kbuf,
                   const double* __restrict__ hn64,
                   float* __restrict__ resval, int* __restrict__ rescol) {
  __shared__ unsigned scand[4][CCAP];
  __shared__ double cres[4][CCAP];
  const int t = threadIdx.x, lane = t & 63, wv = t >> 6;
  const int row = blockIdx.x * 4 + wv;

  unsigned k8[8];
  {
    const unsigned* src = kbuf + (size_t)row * 512 + lane * 8;
    uint4 a = *(const uint4*)(src);
    uint4 b = *(const uint4*)(src + 4);
    k8[0] = a.x; k8[1] = a.y; k8[2] = a.z; k8[3] = a.w;
    k8[4] = b.x; k8[5] = b.y; k8[6] = b.z; k8[7] = b.w;
  }

  unsigned lo = 0, hi = 0xFFFFu;
  while (lo < hi) {
    unsigned mid = (lo + hi + 1) >> 1;
    int c = 0;
    #pragma unroll
    for (int i = 0; i < 8; ++i) c += (int)((k8[i] >> 16) >= mid);
    #pragma unroll
    for (int d = 1; d < 64; d <<= 1) c += __shfl_xor(c, d);
    if (c >= TCAND) lo = mid; else hi = mid - 1;
  }
  const unsigned thr = lo;

  int cl = 0;
  #pragma unroll
  for (int i = 0; i < 8; ++i) cl += (int)((k8[i] >> 16) >= thr);
  int pre = cl;
  #pragma unroll
  for (int d = 1; d < 64; d <<= 1) {
    int y = __shfl_up(pre, d);
    if (lane >= d) pre += y;
  }
  const int total = __shfl(pre, 63);
  const int nc = total < CCAP ? total : CCAP;
  int slot = pre - cl;
  #pragma unroll
  for (int i = 0; i < 8; ++i) {
    if ((k8[i] >> 16) >= thr) {
      if (slot < CCAP) scand[wv][slot] = k8[i];
      ++slot;
    }
  }
  // same-wave LDS producer->consumer: compiler inserts lgkmcnt

  const double* arow = hn64 + (size_t)row * DD;
  const int hl = lane >> 5;
  const int kl = (lane & 31) * 4;
  const double a0 = arow[kl], a1 = arow[kl + 1], a2 = arow[kl + 2], a3 = arow[kl + 3];
  const int ng = (nc + 1) >> 1;
  for (int g = 0; g < ng; ++g) {
    const int ci = 2 * g + hl;
    double partial = 0.0;
    if (ci < nc) {
      const int col = (int)(scand[wv][ci] & 0xFFFFu);
      const double* brow = hn64 + (size_t)col * DD + kl;
      double2 b01 = *(const double2*)(brow);
      double2 b23 = *(const double2*)(brow + 2);
      partial = fma(a0, b01.x, fma(a1, b01.y, fma(a2, b23.x, a3 * b23.y)));
    }
    #pragma unroll
    for (int d = 1; d < 32; d <<= 1)
      partial += __shfl_xor(partial, d);
    if ((lane & 31) == 0 && ci < nc) cres[wv][ci] = partial;
  }
  double rv0 = -1.0e300, rv1 = -1.0e300;
  int rc0 = 0x7fffffff, rc1 = 0x7fffffff;
  if (lane < nc)      { rv0 = cres[wv][lane];      rc0 = (int)(scand[wv][lane] & 0xFFFFu); }
  if (lane + 64 < nc) { rv1 = cres[wv][lane + 64]; rc1 = (int)(scand[wv][lane + 64] & 0xFFFFu); }

  for (int itk = 0; itk < KTOP; ++itk) {
    bool f = (rv0 > rv1) || (rv0 == rv1 && rc0 < rc1);
    double bv = f ? rv0 : rv1;
    int bc = f ? rc0 : rc1;
    #pragma unroll
    for (int d = 1; d < 64; d <<= 1) {
      double ov = __shfl_xor(bv, d);
      int    oc = __shfl_xor(bc, d);
      bool tk = (ov > bv) || (ov == bv && oc < bc);
      bv = tk ? ov : bv;
      bc = tk ? oc : bc;
    }
    if (lane == itk) {
      resval[(size_t)row * KTOP + itk] = (float)fmax(bv, 0.0);
      rescol[(size_t)row * KTOP + itk] = bc;
    }
    if (rv0 == bv && rc0 == bc) rv0 = -1.0e300;
    else if (rv1 == bv && rc1 == bc) rv1 = -1.0e300;
  }
}

// ---------------- Kernel 3: emit all rows (zeros + 31 scattered values) ----------------
__global__ __launch_bounds__(256)
void emit_kernel(const float* __restrict__ resval, const int* __restrict__ rescol,
                 float* __restrict__ out) {
  const int row = blockIdx.x, t = threadIdx.x;
  float v = 0.0f; int c = 0;
  if (t < KTOP) {
    v = resval[(size_t)row * KTOP + t];
    c = rescol[(size_t)row * KTOP + t];
  }
  f32x4* orow = (f32x4*)(out + (size_t)row * NN);
  const f32x4 z = {0.0f, 0.0f, 0.0f, 0.0f};
  #pragma unroll
  for (int i = 0; i < NN / 4 / 256; ++i)
    __builtin_nontemporal_store(z, &orow[i * 256 + t]);
  __syncthreads();   // zeros drained before scatter overwrites
  if (t < KTOP) out[(size_t)row * NN + c] = v;
}

extern "C" void kernel_launch(void* const* d_in, const int* in_sizes, int n_in,
                              void* d_out, int out_size, void* d_ws, size_t ws_size,
                              hipStream_t stream) {
  const float* feat = (const float*)d_in[0];
  const float* W1 = (const float*)d_in[1];
  const float* b1 = (const float*)d_in[2];
  const float* W2 = (const float*)d_in[3];
  const float* b2 = (const float*)d_in[4];
  float* out = (float*)d_out;

  // ws: hn64 (12.6 MB) | hnb (3.1 MB) | resval (1.5 MB) | rescol (1.5 MB) | W1T,W2T (128 KB)
  double* hn64 = (double*)d_ws;
  unsigned short* hnb = (unsigned short*)(hn64 + (size_t)NN * DD);
  float* resval = (float*)(hnb + (size_t)NN * DD);
  int* rescol = (int*)(resval + (size_t)NN * KTOP);
  float* W1T = (float*)(rescol + (size_t)NN * KTOP);
  float* W2T = W1T + DD * DD;

  // kbuf (25 MB): parked in d_out's upper region (byte offset 512 MB of 604 MB);
  // fully consumed by select_kernel before emit overwrites all of d_out.
  unsigned* kbuf = (unsigned*)((char*)d_out + ((size_t)512 << 20));

  wtrans_kernel<<<DD, DD, 0, stream>>>(W1, W2, W1T, W2T);
  mlp_norm_kernel<<<NN / 16, 256, 0, stream>>>(feat, W1T, b1, W2T, b2, hn64, hnb);
  simladder_kernel<<<NN / RPB, 512, 0, stream>>>(hnb, kbuf);
  select_kernel<<<NN / 4, 256, 0, stream>>>(kbuf, hn64, resval, rescol);
  emit_kernel<<<NN, 256, 0, stream>>>(resval, rescol, out);
}